// Round 11
// baseline (46.689 us; speedup 1.0000x reference)
//
#include <hip/hip_runtime.h>
#include <hip/hip_bf16.h>

// Problem constants (match reference)
constexpr int P = 8192;
constexpr int G = 4096;
constexpr int BLK = 256;
constexpr int GSPLIT = 128;         // G-dimension parallel chunks
constexpr int CHUNK = G / GSPLIT;   // 32 gaussians per chunk
constexpr int PPT = 4;              // points per thread
constexpr int PBLK = BLK * PPT;     // 1024 points per block
constexpr float LOG2E = 1.4426950408889634f;

typedef float sf4 __attribute__((ext_vector_type(4)));

// Single-instruction exp2 (v_exp_f32 IS 2^x; verified -4us in R9 vs exp2f's
// __ocml range-reduction expansion).
__device__ __forceinline__ float fast_exp2(float x) {
  float r;
  asm("v_exp_f32 %0, %1" : "=v"(r) : "v"(x));
  return r;
}

// ---------------------------------------------------------------------------
// Kernel 1: per-Gaussian precompute -> pre[] (20 floats = 5 x float4 each):
//   [0]: mean.x, mean.y, mean.z, w00
//   [1]: w11, w22, w01, w02
//   [2]: w12, a0, a1, a2
//   [3]: a3, qxy, qyz, qxz
//   [4]: qxx, qyy, qzz, 0
// wij: Mahalanobis coeffs with (-0.5*log2e) and off-diag 2x folded ->
//   gauss = exp2(w00 dxx + w11 dyy + w22 dzz + w01 dxdy + w02 dxdz + w12 dydz)
// SH quad folded onto the same 6 monomials (qxx=a8-a6 etc);
//   feat = a0 + inv*lin + inv2*quad.
// ---------------------------------------------------------------------------
__global__ __launch_bounds__(256) void precomp_kernel(
    const float* __restrict__ mean, const float* __restrict__ fdc,
    const float* __restrict__ frest, const float* __restrict__ scal,
    const float* __restrict__ rot, const float* __restrict__ opac,
    float4* __restrict__ pre) {
  int g = blockIdx.x * blockDim.x + threadIdx.x;
  if (g >= G) return;

  float qr = rot[g * 4 + 0], qx = rot[g * 4 + 1];
  float qy = rot[g * 4 + 2], qz = rot[g * 4 + 3];
  float qn = 1.0f / sqrtf(qr * qr + qx * qx + qy * qy + qz * qz);
  qr *= qn; qx *= qn; qy *= qn; qz *= qn;

  float R00 = 1.f - 2.f * (qy * qy + qz * qz);
  float R01 = 2.f * (qx * qy - qr * qz);
  float R02 = 2.f * (qx * qz + qr * qy);
  float R10 = 2.f * (qx * qy + qr * qz);
  float R11 = 1.f - 2.f * (qx * qx + qz * qz);
  float R12 = 2.f * (qy * qz - qr * qx);
  float R20 = 2.f * (qx * qz - qr * qy);
  float R21 = 2.f * (qy * qz + qr * qx);
  float R22 = 1.f - 2.f * (qx * qx + qy * qy);

  float sc0 = expf(scal[g * 3 + 0]);
  float sc1 = expf(scal[g * 3 + 1]);
  float sc2 = expf(scal[g * 3 + 2]);
  float iv0 = 1.0f / (sc0 * sc0);
  float iv1 = 1.0f / (sc1 * sc1);
  float iv2 = 1.0f / (sc2 * sc2);

  float s00 = R00 * R00 * iv0 + R01 * R01 * iv1 + R02 * R02 * iv2;
  float s11 = R10 * R10 * iv0 + R11 * R11 * iv1 + R12 * R12 * iv2;
  float s22 = R20 * R20 * iv0 + R21 * R21 * iv1 + R22 * R22 * iv2;
  float s01 = R00 * R10 * iv0 + R01 * R11 * iv1 + R02 * R12 * iv2;
  float s02 = R00 * R20 * iv0 + R01 * R21 * iv1 + R02 * R22 * iv2;
  float s12 = R10 * R20 * iv0 + R11 * R21 * iv1 + R12 * R22 * iv2;

  const float kD = -0.5f * LOG2E;
  const float kO = -LOG2E;

  float alpha = 1.0f / (1.0f + expf(-opac[g]));

  const float C0 = 0.28209479177387814f;
  const float C1 = 0.4886025119029199f;
  float a0 = C0 * fdc[g] * alpha;
  float a1 = -C1 * frest[g * 8 + 0] * alpha;
  float a2 =  C1 * frest[g * 8 + 1] * alpha;
  float a3 = -C1 * frest[g * 8 + 2] * alpha;
  float a4 =  1.0925484305920792f  * frest[g * 8 + 3] * alpha;
  float a5 = -1.0925484305920792f  * frest[g * 8 + 4] * alpha;
  float a6 =  0.31539156525252005f * frest[g * 8 + 5] * alpha;
  float a7 = -1.0925484305920792f  * frest[g * 8 + 6] * alpha;
  float a8 =  0.5462742152960396f  * frest[g * 8 + 7] * alpha;

  float mx = mean[g * 3 + 0], my = mean[g * 3 + 1], mz = mean[g * 3 + 2];

  pre[g * 5 + 0] = make_float4(mx, my, mz, kD * s00);
  pre[g * 5 + 1] = make_float4(kD * s11, kD * s22, kO * s01, kO * s02);
  pre[g * 5 + 2] = make_float4(kO * s12, a0, a1, a2);
  pre[g * 5 + 3] = make_float4(a3, a4, a5, a7);                    // a3,qxy,qyz,qxz
  pre[g * 5 + 4] = make_float4(a8 - a6, -a8 - a6, 2.f * a6, 0.f);  // qxx,qyy,qzz
}

// ---------------------------------------------------------------------------
// Kernel 2: main pair loop, SGPR-coefficient version. Grid (8,128) = 1024
// blocks, 4/CU. NO LDS: per gaussian, one inline-asm block issues 5x
// s_load_dwordx4 (wave-uniform address, scalar pipe, K$-resident 2.5 KB
// chunk) + s_waitcnt INSIDE the block (consumers data-depend on the asm
// outputs -> no hoisting hazard). "=&s" EARLY-CLOBBER is load-bearing:
// without it the allocator may overlap an output quad with the address pair
// %5, and load #1 corrupts the address for loads #2-5 (R10's core dump).
// Every v_fma takes its coefficient as the free SGPR operand -> VALU is the
// only loaded pipe (R7-R9 evidence: LDS 12.8us + VALU 13.2us serialized).
// ---------------------------------------------------------------------------
__global__ __launch_bounds__(BLK) void main_kernel(
    const float* __restrict__ pos, const float* __restrict__ pre,
    float* __restrict__ partial) {
  const int t = threadIdx.x;
  const int c = blockIdx.y;
  const int pbase = blockIdx.x * PBLK + t;

  const float* __restrict__ gbase = pre + (size_t)c * CHUNK * 20;

  float px[PPT], py[PPT], pz[PPT], acc[PPT];
#pragma unroll
  for (int k = 0; k < PPT; ++k) {
    const int p = pbase + k * BLK;
    px[k] = pos[p * 3 + 0] * 2.0f - 1.0f;
    py[k] = pos[p * 3 + 1] * 2.0f - 1.0f;
    pz[k] = pos[p * 3 + 2] * 2.0f - 1.0f;
    acc[k] = 0.0f;
  }

#pragma unroll 2
  for (int gi = 0; gi < CHUNK; ++gi) {
    sf4 b0, b1, b2, b3, b4;
    const float* ga = gbase + gi * 20;
    asm volatile(
        "s_load_dwordx4 %0, %5, 0x0\n\t"
        "s_load_dwordx4 %1, %5, 0x10\n\t"
        "s_load_dwordx4 %2, %5, 0x20\n\t"
        "s_load_dwordx4 %3, %5, 0x30\n\t"
        "s_load_dwordx4 %4, %5, 0x40\n\t"
        "s_waitcnt lgkmcnt(0)"
        : "=&s"(b0), "=&s"(b1), "=&s"(b2), "=&s"(b3), "=&s"(b4)
        : "s"(ga));

#pragma unroll
    for (int k = 0; k < PPT; ++k) {
      const float dx = px[k] - b0.x, dy = py[k] - b0.y, dz = pz[k] - b0.z;
      const float dxx = dx * dx, dyy = dy * dy, dzz = dz * dz;
      const float dxdy = dx * dy, dxdz = dx * dz, dydz = dy * dz;
      const float d2 = dxx + dyy + dzz;

      float m = b0.w * dxx;
      m = fmaf(b1.x, dyy, m);
      m = fmaf(b1.y, dzz, m);
      m = fmaf(b1.z, dxdy, m);
      m = fmaf(b1.w, dxdz, m);
      m = fmaf(b2.x, dydz, m);
      const float gauss = fast_exp2(m);

      const float inv = __builtin_amdgcn_rsqf(fmaxf(d2, 1e-16f));
      const float inv2 = inv * inv;

      float lin = b2.z * dy;                 // a1*dy
      lin = fmaf(b2.w, dz, lin);             // a2*dz
      lin = fmaf(b3.x, dx, lin);             // a3*dx

      float quad = b3.y * dxdy;              // qxy*dxdy
      quad = fmaf(b3.z, dydz, quad);         // qyz*dydz
      quad = fmaf(b3.w, dxdz, quad);         // qxz*dxdz
      quad = fmaf(b4.x, dxx, quad);          // qxx*dxx
      quad = fmaf(b4.y, dyy, quad);          // qyy*dyy
      quad = fmaf(b4.z, dzz, quad);          // qzz*dzz

      float feat = fmaf(inv, lin, b2.y);     // a0 + inv*lin
      feat = fmaf(inv2, quad, feat);

      acc[k] = fmaf(gauss, feat, acc[k]);
    }
  }

#pragma unroll
  for (int k = 0; k < PPT; ++k) {
    partial[(size_t)c * P + pbase + k * BLK] = acc[k];
  }
}

// ---------------------------------------------------------------------------
// Two-level parallel reduction over GSPLIT=128 partials (R7 champion).
// 128 blocks x 256 thr; slice s = t>>6 sums contiguous c-range
// [s*32, s*32+32) for point p = blk*64 + (t&63), 4 accumulator chains.
// Fixed combine order -> deterministic.
// ---------------------------------------------------------------------------
__global__ __launch_bounds__(256) void reduce_kernel(
    const float* __restrict__ partial, float* __restrict__ out) {
  __shared__ float red[4][64];
  const int t = threadIdx.x;
  const int lane = t & 63;
  const int s = t >> 6;
  const int p = blockIdx.x * 64 + lane;
  const int cbase = s * 32;

  float a0 = 0.f, a1 = 0.f, a2 = 0.f, a3 = 0.f;
#pragma unroll
  for (int j = 0; j < 32; j += 4) {
    a0 += partial[(size_t)(cbase + j + 0) * P + p];
    a1 += partial[(size_t)(cbase + j + 1) * P + p];
    a2 += partial[(size_t)(cbase + j + 2) * P + p];
    a3 += partial[(size_t)(cbase + j + 3) * P + p];
  }
  red[s][lane] = (a0 + a1) + (a2 + a3);
  __syncthreads();

  if (t < 64) {
    out[p] = (red[0][lane] + red[1][lane]) + (red[2][lane] + red[3][lane]);
  }
}

extern "C" void kernel_launch(void* const* d_in, const int* in_sizes, int n_in,
                              void* d_out, int out_size, void* d_ws, size_t ws_size,
                              hipStream_t stream) {
  const float* pos   = (const float*)d_in[0];  // position_rx (P,3)
  const float* mean  = (const float*)d_in[1];  // mean (G,3)
  const float* fdc   = (const float*)d_in[2];  // features_dc (G,1,1)
  const float* frest = (const float*)d_in[3];  // features_rest (G,1,8)
  const float* scal  = (const float*)d_in[4];  // scaling (G,3)
  const float* rot   = (const float*)d_in[5];  // rotation (G,4)
  const float* opac  = (const float*)d_in[6];  // opacity (G,1)
  float* out = (float*)d_out;                  // (P,1) fp32

  float4* pre = (float4*)d_ws;                 // G*5*16 = 320 KB
  float* partial = (float*)((char*)d_ws + (size_t)G * 5 * sizeof(float4));  // 4 MB

  precomp_kernel<<<G / 256, 256, 0, stream>>>(mean, fdc, frest, scal, rot, opac, pre);
  main_kernel<<<dim3(P / PBLK, GSPLIT), BLK, 0, stream>>>(pos, (const float*)pre, partial);
  reduce_kernel<<<P / 64, 256, 0, stream>>>(partial, out);
}

// Round 12
// 30.898 us; speedup vs baseline: 1.5111x; 1.5111x over previous
//
#include <hip/hip_runtime.h>
#include <hip/hip_bf16.h>

// Problem constants (match reference)
constexpr int P = 8192;
constexpr int G = 4096;
constexpr int BLK = 256;
constexpr int GSPLIT = 128;         // G-dimension parallel chunks (champion)
constexpr int CHUNK = G / GSPLIT;   // 32 gaussians per chunk
constexpr int PPT = 4;              // points per thread (2 x packed pairs)
constexpr int PBLK = BLK * PPT;     // 1024 points per block
constexpr float LOG2E = 1.4426950408889634f;

// Packed fp32 pair: gfx950 has VOP3P v_pk_{fma,mul,add,max}_f32 -- one
// instruction processes 2 floats/lane at the same 2-cyc issue as scalar.
// clang lowers <2 x float> arithmetic (incl. fmuladd contraction) to these.
typedef float v2f __attribute__((ext_vector_type(2)));

// Single-instruction exp2 (v_exp_f32 IS 2^x; verified -4us in R9 vs exp2f's
// __ocml range-reduction expansion).
__device__ __forceinline__ float fast_exp2(float x) {
  float r;
  asm("v_exp_f32 %0, %1" : "=v"(r) : "v"(x));
  return r;
}

// ---------------------------------------------------------------------------
// Fused kernel (R9 champion structure + packed-f32 inner loop).
// Grid = (P/PBLK, GSPLIT) = (8, 128) = 1024 blocks, 4/CU, 4 waves/SIMD.
// R11 evidence: VALUBusy*dur = 22us/SIMD vs 16.6us inner-loop arithmetic
// -> the kernel is VALU-issue-bound; packing halves the packable 31 insts.
// Per-gaussian coefficients (5 x float4 in LDS, broadcast ds_read_b128):
//   v0: mean.x, mean.y, mean.z, w00
//   v1: w11, w22, w01, w02
//   v2: w12, a0, a1, a2
//   v3: a3, qxy, qyz, qxz
//   v4: qxx, qyy, qzz, 0
// gauss = exp2(w00 dxx + w11 dyy + w22 dzz + w01 dxdy + w02 dxdz + w12 dydz)
// feat  = a0 + inv*lin + inv2*quad  (SH on the same 6 monomials)
// ---------------------------------------------------------------------------
__global__ __launch_bounds__(BLK) void fused_main(
    const float* __restrict__ pos,
    const float* __restrict__ mean, const float* __restrict__ fdc,
    const float* __restrict__ frest, const float* __restrict__ scal,
    const float* __restrict__ rot, const float* __restrict__ opac,
    float* __restrict__ partial) {
  __shared__ float4 sg[CHUNK * 5];

  const int t = threadIdx.x;
  const int c = blockIdx.y;
  const int pbase = blockIdx.x * PBLK + t;

  // Points packed in pairs: pxv[h] holds points (2h, 2h+1); loads issued
  // first so their latency overlaps the precompute.
  v2f pxv[2], pyv[2], pzv[2], accv[2];
#pragma unroll
  for (int h = 0; h < 2; ++h) {
    const int pA = pbase + (2 * h + 0) * BLK;
    const int pB = pbase + (2 * h + 1) * BLK;
    v2f x = {pos[pA * 3 + 0], pos[pB * 3 + 0]};
    v2f y = {pos[pA * 3 + 1], pos[pB * 3 + 1]};
    v2f z = {pos[pA * 3 + 2], pos[pB * 3 + 2]};
    pxv[h] = x * 2.0f - 1.0f;
    pyv[h] = y * 2.0f - 1.0f;
    pzv[h] = z * 2.0f - 1.0f;
    accv[h] = (v2f){0.f, 0.f};
  }

  // In-block precompute of this chunk's 32 gaussians (8x redundant across
  // blockIdx.x; ~500 cycles, negligible).
  if (t < CHUNK) {
    const int g = c * CHUNK + t;

    float qr = rot[g * 4 + 0], qx = rot[g * 4 + 1];
    float qy = rot[g * 4 + 2], qz = rot[g * 4 + 3];
    float qn = 1.0f / sqrtf(qr * qr + qx * qx + qy * qy + qz * qz);
    qr *= qn; qx *= qn; qy *= qn; qz *= qn;

    float R00 = 1.f - 2.f * (qy * qy + qz * qz);
    float R01 = 2.f * (qx * qy - qr * qz);
    float R02 = 2.f * (qx * qz + qr * qy);
    float R10 = 2.f * (qx * qy + qr * qz);
    float R11 = 1.f - 2.f * (qx * qx + qz * qz);
    float R12 = 2.f * (qy * qz - qr * qx);
    float R20 = 2.f * (qx * qz - qr * qy);
    float R21 = 2.f * (qy * qz + qr * qx);
    float R22 = 1.f - 2.f * (qx * qx + qy * qy);

    float sc0 = expf(scal[g * 3 + 0]);
    float sc1 = expf(scal[g * 3 + 1]);
    float sc2 = expf(scal[g * 3 + 2]);
    float iv0 = 1.0f / (sc0 * sc0);
    float iv1 = 1.0f / (sc1 * sc1);
    float iv2 = 1.0f / (sc2 * sc2);

    float s00 = R00 * R00 * iv0 + R01 * R01 * iv1 + R02 * R02 * iv2;
    float s11 = R10 * R10 * iv0 + R11 * R11 * iv1 + R12 * R12 * iv2;
    float s22 = R20 * R20 * iv0 + R21 * R21 * iv1 + R22 * R22 * iv2;
    float s01 = R00 * R10 * iv0 + R01 * R11 * iv1 + R02 * R12 * iv2;
    float s02 = R00 * R20 * iv0 + R01 * R21 * iv1 + R02 * R22 * iv2;
    float s12 = R10 * R20 * iv0 + R11 * R21 * iv1 + R12 * R22 * iv2;

    const float kD = -0.5f * LOG2E;
    const float kO = -LOG2E;

    float alpha = 1.0f / (1.0f + expf(-opac[g]));

    const float C0 = 0.28209479177387814f;
    const float C1 = 0.4886025119029199f;
    float a0 = C0 * fdc[g] * alpha;
    float a1 = -C1 * frest[g * 8 + 0] * alpha;
    float a2 =  C1 * frest[g * 8 + 1] * alpha;
    float a3 = -C1 * frest[g * 8 + 2] * alpha;
    float a4 =  1.0925484305920792f  * frest[g * 8 + 3] * alpha;
    float a5 = -1.0925484305920792f  * frest[g * 8 + 4] * alpha;
    float a6 =  0.31539156525252005f * frest[g * 8 + 5] * alpha;
    float a7 = -1.0925484305920792f  * frest[g * 8 + 6] * alpha;
    float a8 =  0.5462742152960396f  * frest[g * 8 + 7] * alpha;

    float mx = mean[g * 3 + 0], my = mean[g * 3 + 1], mz = mean[g * 3 + 2];

    sg[t * 5 + 0] = make_float4(mx, my, mz, kD * s00);
    sg[t * 5 + 1] = make_float4(kD * s11, kD * s22, kO * s01, kO * s02);
    sg[t * 5 + 2] = make_float4(kO * s12, a0, a1, a2);
    sg[t * 5 + 3] = make_float4(a3, a4, a5, a7);                    // a3,qxy,qyz,qxz
    sg[t * 5 + 4] = make_float4(a8 - a6, -a8 - a6, 2.f * a6, 0.f);  // qxx,qyy,qzz
  }

  __syncthreads();

#pragma unroll 2
  for (int gi = 0; gi < CHUNK; ++gi) {
    const float4 v0 = sg[gi * 5 + 0];
    const float4 v1 = sg[gi * 5 + 1];
    const float4 v2 = sg[gi * 5 + 2];
    const float4 v3 = sg[gi * 5 + 3];
    const float4 v4 = sg[gi * 5 + 4];

#pragma unroll
    for (int h = 0; h < 2; ++h) {
      // scalar coefficients splat across the packed pair -> v_pk_* ops
      const v2f dx = pxv[h] - v0.x;
      const v2f dy = pyv[h] - v0.y;
      const v2f dz = pzv[h] - v0.z;
      const v2f dxx = dx * dx, dyy = dy * dy, dzz = dz * dz;
      const v2f dxdy = dx * dy, dxdz = dx * dz, dydz = dy * dz;
      const v2f d2 = dxx + dyy + dzz;

      v2f m = v0.w * dxx;
      m = v1.x * dyy + m;
      m = v1.y * dzz + m;
      m = v1.z * dxdy + m;
      m = v1.w * dxdz + m;
      m = v2.x * dydz + m;
      v2f gauss;
      gauss.x = fast_exp2(m.x);
      gauss.y = fast_exp2(m.y);

      const v2f d2c = __builtin_elementwise_max(d2, (v2f){1e-16f, 1e-16f});
      v2f inv;
      inv.x = __builtin_amdgcn_rsqf(d2c.x);
      inv.y = __builtin_amdgcn_rsqf(d2c.y);
      const v2f inv2 = inv * inv;

      v2f lin = v2.z * dy;                 // a1*dy
      lin = v2.w * dz + lin;               // a2*dz
      lin = v3.x * dx + lin;               // a3*dx

      v2f quad = v3.y * dxdy;              // qxy*dxdy
      quad = v3.z * dydz + quad;           // qyz*dydz
      quad = v3.w * dxdz + quad;           // qxz*dxdz
      quad = v4.x * dxx + quad;            // qxx*dxx
      quad = v4.y * dyy + quad;            // qyy*dyy
      quad = v4.z * dzz + quad;            // qzz*dzz

      v2f feat = inv * lin + v2.y;         // a0 + inv*lin
      feat = inv2 * quad + feat;

      accv[h] = gauss * feat + accv[h];
    }
  }

#pragma unroll
  for (int h = 0; h < 2; ++h) {
    partial[(size_t)c * P + pbase + (2 * h + 0) * BLK] = accv[h].x;
    partial[(size_t)c * P + pbase + (2 * h + 1) * BLK] = accv[h].y;
  }
}

// ---------------------------------------------------------------------------
// Two-level parallel reduction over GSPLIT=128 partials (R7 champion).
// 128 blocks x 256 thr; slice s = t>>6 sums contiguous c-range
// [s*32, s*32+32) for point p = blk*64 + (t&63), 4 accumulator chains.
// Fixed combine order -> deterministic.
// ---------------------------------------------------------------------------
__global__ __launch_bounds__(256) void reduce_kernel(
    const float* __restrict__ partial, float* __restrict__ out) {
  __shared__ float red[4][64];
  const int t = threadIdx.x;
  const int lane = t & 63;
  const int s = t >> 6;
  const int p = blockIdx.x * 64 + lane;
  const int cbase = s * 32;

  float a0 = 0.f, a1 = 0.f, a2 = 0.f, a3 = 0.f;
#pragma unroll
  for (int j = 0; j < 32; j += 4) {
    a0 += partial[(size_t)(cbase + j + 0) * P + p];
    a1 += partial[(size_t)(cbase + j + 1) * P + p];
    a2 += partial[(size_t)(cbase + j + 2) * P + p];
    a3 += partial[(size_t)(cbase + j + 3) * P + p];
  }
  red[s][lane] = (a0 + a1) + (a2 + a3);
  __syncthreads();

  if (t < 64) {
    out[p] = (red[0][lane] + red[1][lane]) + (red[2][lane] + red[3][lane]);
  }
}

extern "C" void kernel_launch(void* const* d_in, const int* in_sizes, int n_in,
                              void* d_out, int out_size, void* d_ws, size_t ws_size,
                              hipStream_t stream) {
  const float* pos   = (const float*)d_in[0];  // position_rx (P,3)
  const float* mean  = (const float*)d_in[1];  // mean (G,3)
  const float* fdc   = (const float*)d_in[2];  // features_dc (G,1,1)
  const float* frest = (const float*)d_in[3];  // features_rest (G,1,8)
  const float* scal  = (const float*)d_in[4];  // scaling (G,3)
  const float* rot   = (const float*)d_in[5];  // rotation (G,4)
  const float* opac  = (const float*)d_in[6];  // opacity (G,1)
  float* out = (float*)d_out;                  // (P,1) fp32

  float* partial = (float*)d_ws;               // GSPLIT*P*4 = 4 MB

  fused_main<<<dim3(P / PBLK, GSPLIT), BLK, 0, stream>>>(
      pos, mean, fdc, frest, scal, rot, opac, partial);
  reduce_kernel<<<P / 64, 256, 0, stream>>>(partial, out);
}

// Round 13
// 30.814 us; speedup vs baseline: 1.5152x; 1.0027x over previous
//
#include <hip/hip_runtime.h>
#include <hip/hip_bf16.h>

// Problem constants (match reference)
constexpr int P = 8192;
constexpr int G = 4096;
constexpr int BLK = 256;
constexpr int GSPLIT = 128;         // G-dimension parallel chunks
constexpr int CHUNK = G / GSPLIT;   // 32 gaussians per chunk
constexpr int PPT = 8;              // points per thread (4 packed halves)
constexpr int NH = PPT / 2;         // packed halves
constexpr int PBLK = BLK * PPT;     // 2048 points per block
constexpr float LOG2E = 1.4426950408889634f;

// Packed fp32 pair: gfx950 VOP3P v_pk_{fma,mul,add}_f32 -- one instruction,
// 2 floats/lane, same 2-cyc issue as scalar (verified -3.8us in R12).
typedef float v2f __attribute__((ext_vector_type(2)));

// Single-instruction exp2 (v_exp_f32 IS 2^x; verified -4us in R9).
__device__ __forceinline__ float fast_exp2(float x) {
  float r;
  asm("v_exp_f32 %0, %1" : "=v"(r) : "v"(x));
  return r;
}

// ---------------------------------------------------------------------------
// Fused kernel. Grid = (P/PBLK, GSPLIT) = (4, 128) = 512 blocks, 2/CU,
// 2 waves/SIMD. PPT=8 rationale (R12 post-mortem): after v_pk packing the
// pipe balance per CU was LDS 12.8us / VALU 6.6us / trans 3.4us -- LDS
// dominates, and LDS cost scales with waves*iters, so the only cut is more
// points per wave. At PPT=8: LDS 6.4 / VALU 6.6 / trans 3.4 -- balanced.
// ILP: 4 independent packed half-chains per thread cover latency at
// 2 waves/SIMD.
// Per-gaussian coefficients (5 x float4 in LDS, broadcast ds_read_b128):
//   v0: mean.x, mean.y, mean.z, w00
//   v1: w11, w22, w01, w02
//   v2: w12, a0, a1, a2
//   v3: a3, qxy, qyz, qxz
//   v4: qxx, qyy, qzz, 0
// gauss = exp2(w00 dxx + w11 dyy + w22 dzz + w01 dxdy + w02 dxdz + w12 dydz)
// feat  = a0 + inv*lin + inv2*quad  (SH on the same 6 monomials)
// ---------------------------------------------------------------------------
__global__ __launch_bounds__(BLK) void fused_main(
    const float* __restrict__ pos,
    const float* __restrict__ mean, const float* __restrict__ fdc,
    const float* __restrict__ frest, const float* __restrict__ scal,
    const float* __restrict__ rot, const float* __restrict__ opac,
    float* __restrict__ partial) {
  __shared__ float4 sg[CHUNK * 5];

  const int t = threadIdx.x;
  const int c = blockIdx.y;
  const int pbase = blockIdx.x * PBLK + t;

  // Points packed in pairs: h holds points (2h, 2h+1)*BLK offsets; loads
  // issued first so their latency overlaps the precompute.
  v2f pxv[NH], pyv[NH], pzv[NH], accv[NH];
#pragma unroll
  for (int h = 0; h < NH; ++h) {
    const int pA = pbase + (2 * h + 0) * BLK;
    const int pB = pbase + (2 * h + 1) * BLK;
    v2f x = {pos[pA * 3 + 0], pos[pB * 3 + 0]};
    v2f y = {pos[pA * 3 + 1], pos[pB * 3 + 1]};
    v2f z = {pos[pA * 3 + 2], pos[pB * 3 + 2]};
    pxv[h] = x * 2.0f - 1.0f;
    pyv[h] = y * 2.0f - 1.0f;
    pzv[h] = z * 2.0f - 1.0f;
    accv[h] = (v2f){0.f, 0.f};
  }

  // In-block precompute of this chunk's 32 gaussians (4x redundant across
  // blockIdx.x; ~500 cycles, negligible).
  if (t < CHUNK) {
    const int g = c * CHUNK + t;

    float qr = rot[g * 4 + 0], qx = rot[g * 4 + 1];
    float qy = rot[g * 4 + 2], qz = rot[g * 4 + 3];
    float qn = 1.0f / sqrtf(qr * qr + qx * qx + qy * qy + qz * qz);
    qr *= qn; qx *= qn; qy *= qn; qz *= qn;

    float R00 = 1.f - 2.f * (qy * qy + qz * qz);
    float R01 = 2.f * (qx * qy - qr * qz);
    float R02 = 2.f * (qx * qz + qr * qy);
    float R10 = 2.f * (qx * qy + qr * qz);
    float R11 = 1.f - 2.f * (qx * qx + qz * qz);
    float R12 = 2.f * (qy * qz - qr * qx);
    float R20 = 2.f * (qx * qz - qr * qy);
    float R21 = 2.f * (qy * qz + qr * qx);
    float R22 = 1.f - 2.f * (qx * qx + qy * qy);

    float sc0 = expf(scal[g * 3 + 0]);
    float sc1 = expf(scal[g * 3 + 1]);
    float sc2 = expf(scal[g * 3 + 2]);
    float iv0 = 1.0f / (sc0 * sc0);
    float iv1 = 1.0f / (sc1 * sc1);
    float iv2 = 1.0f / (sc2 * sc2);

    float s00 = R00 * R00 * iv0 + R01 * R01 * iv1 + R02 * R02 * iv2;
    float s11 = R10 * R10 * iv0 + R11 * R11 * iv1 + R12 * R12 * iv2;
    float s22 = R20 * R20 * iv0 + R21 * R21 * iv1 + R22 * R22 * iv2;
    float s01 = R00 * R10 * iv0 + R01 * R11 * iv1 + R02 * R12 * iv2;
    float s02 = R00 * R20 * iv0 + R01 * R21 * iv1 + R02 * R22 * iv2;
    float s12 = R10 * R20 * iv0 + R11 * R21 * iv1 + R12 * R22 * iv2;

    const float kD = -0.5f * LOG2E;
    const float kO = -LOG2E;

    float alpha = 1.0f / (1.0f + expf(-opac[g]));

    const float C0 = 0.28209479177387814f;
    const float C1 = 0.4886025119029199f;
    float a0 = C0 * fdc[g] * alpha;
    float a1 = -C1 * frest[g * 8 + 0] * alpha;
    float a2 =  C1 * frest[g * 8 + 1] * alpha;
    float a3 = -C1 * frest[g * 8 + 2] * alpha;
    float a4 =  1.0925484305920792f  * frest[g * 8 + 3] * alpha;
    float a5 = -1.0925484305920792f  * frest[g * 8 + 4] * alpha;
    float a6 =  0.31539156525252005f * frest[g * 8 + 5] * alpha;
    float a7 = -1.0925484305920792f  * frest[g * 8 + 6] * alpha;
    float a8 =  0.5462742152960396f  * frest[g * 8 + 7] * alpha;

    float mx = mean[g * 3 + 0], my = mean[g * 3 + 1], mz = mean[g * 3 + 2];

    sg[t * 5 + 0] = make_float4(mx, my, mz, kD * s00);
    sg[t * 5 + 1] = make_float4(kD * s11, kD * s22, kO * s01, kO * s02);
    sg[t * 5 + 2] = make_float4(kO * s12, a0, a1, a2);
    sg[t * 5 + 3] = make_float4(a3, a4, a5, a7);                    // a3,qxy,qyz,qxz
    sg[t * 5 + 4] = make_float4(a8 - a6, -a8 - a6, 2.f * a6, 0.f);  // qxx,qyy,qzz
  }

  __syncthreads();

#pragma unroll 2
  for (int gi = 0; gi < CHUNK; ++gi) {
    const float4 v0 = sg[gi * 5 + 0];
    const float4 v1 = sg[gi * 5 + 1];
    const float4 v2 = sg[gi * 5 + 2];
    const float4 v3 = sg[gi * 5 + 3];
    const float4 v4 = sg[gi * 5 + 4];

#pragma unroll
    for (int h = 0; h < NH; ++h) {
      // scalar coefficients splat across the packed pair -> v_pk_* ops
      const v2f dx = pxv[h] - v0.x;
      const v2f dy = pyv[h] - v0.y;
      const v2f dz = pzv[h] - v0.z;
      const v2f dxx = dx * dx, dyy = dy * dy, dzz = dz * dz;
      const v2f dxdy = dx * dy, dxdz = dx * dz, dydz = dy * dz;
      const v2f d2 = dxx + dyy + dzz;

      v2f m = v0.w * dxx;
      m = v1.x * dyy + m;
      m = v1.y * dzz + m;
      m = v1.z * dxdy + m;
      m = v1.w * dxdz + m;
      m = v2.x * dydz + m;
      v2f gauss;
      gauss.x = fast_exp2(m.x);
      gauss.y = fast_exp2(m.y);

      const v2f d2c = __builtin_elementwise_max(d2, (v2f){1e-16f, 1e-16f});
      v2f inv;
      inv.x = __builtin_amdgcn_rsqf(d2c.x);
      inv.y = __builtin_amdgcn_rsqf(d2c.y);
      const v2f inv2 = inv * inv;

      v2f lin = v2.z * dy;                 // a1*dy
      lin = v2.w * dz + lin;               // a2*dz
      lin = v3.x * dx + lin;               // a3*dx

      v2f quad = v3.y * dxdy;              // qxy*dxdy
      quad = v3.z * dydz + quad;           // qyz*dydz
      quad = v3.w * dxdz + quad;           // qxz*dxdz
      quad = v4.x * dxx + quad;            // qxx*dxx
      quad = v4.y * dyy + quad;            // qyy*dyy
      quad = v4.z * dzz + quad;            // qzz*dzz

      v2f feat = inv * lin + v2.y;         // a0 + inv*lin
      feat = inv2 * quad + feat;

      accv[h] = gauss * feat + accv[h];
    }
  }

#pragma unroll
  for (int h = 0; h < NH; ++h) {
    partial[(size_t)c * P + pbase + (2 * h + 0) * BLK] = accv[h].x;
    partial[(size_t)c * P + pbase + (2 * h + 1) * BLK] = accv[h].y;
  }
}

// ---------------------------------------------------------------------------
// Two-level parallel reduction over GSPLIT=128 partials (R7 champion).
// 128 blocks x 256 thr; slice s = t>>6 sums contiguous c-range
// [s*32, s*32+32) for point p = blk*64 + (t&63), 4 accumulator chains.
// Fixed combine order -> deterministic.
// ---------------------------------------------------------------------------
__global__ __launch_bounds__(256) void reduce_kernel(
    const float* __restrict__ partial, float* __restrict__ out) {
  __shared__ float red[4][64];
  const int t = threadIdx.x;
  const int lane = t & 63;
  const int s = t >> 6;
  const int p = blockIdx.x * 64 + lane;
  const int cbase = s * 32;

  float a0 = 0.f, a1 = 0.f, a2 = 0.f, a3 = 0.f;
#pragma unroll
  for (int j = 0; j < 32; j += 4) {
    a0 += partial[(size_t)(cbase + j + 0) * P + p];
    a1 += partial[(size_t)(cbase + j + 1) * P + p];
    a2 += partial[(size_t)(cbase + j + 2) * P + p];
    a3 += partial[(size_t)(cbase + j + 3) * P + p];
  }
  red[s][lane] = (a0 + a1) + (a2 + a3);
  __syncthreads();

  if (t < 64) {
    out[p] = (red[0][lane] + red[1][lane]) + (red[2][lane] + red[3][lane]);
  }
}

extern "C" void kernel_launch(void* const* d_in, const int* in_sizes, int n_in,
                              void* d_out, int out_size, void* d_ws, size_t ws_size,
                              hipStream_t stream) {
  const float* pos   = (const float*)d_in[0];  // position_rx (P,3)
  const float* mean  = (const float*)d_in[1];  // mean (G,3)
  const float* fdc   = (const float*)d_in[2];  // features_dc (G,1,1)
  const float* frest = (const float*)d_in[3];  // features_rest (G,1,8)
  const float* scal  = (const float*)d_in[4];  // scaling (G,3)
  const float* rot   = (const float*)d_in[5];  // rotation (G,4)
  const float* opac  = (const float*)d_in[6];  // opacity (G,1)
  float* out = (float*)d_out;                  // (P,1) fp32

  float* partial = (float*)d_ws;               // GSPLIT*P*4 = 4 MB

  fused_main<<<dim3(P / PBLK, GSPLIT), BLK, 0, stream>>>(
      pos, mean, fdc, frest, scal, rot, opac, partial);
  reduce_kernel<<<P / 64, 256, 0, stream>>>(partial, out);
}